// Round 15
// baseline (90.889 us; speedup 1.0000x reference)
//
#include <hip/hip_runtime.h>
#include <stdint.h>
#include <stddef.h>

// B=4, T=2048, C=256, H=64, D=4 ; rows = 8192 ; qkv row = [q|k|v] 768 f
typedef __attribute__((ext_vector_type(8))) short short8;
typedef __attribute__((ext_vector_type(4))) float floatx4;

// ---------------------------------------------------------------------------
// Host-side np.random.default_rng(1234) op list (verified R2).
// ---------------------------------------------------------------------------
static void compute_ops_host(int* kinds, int* wires) {
  const uint32_t MULT_A = 0x931e8875u;
  const uint32_t INIT_B = 0x8b51f9ddu, MULT_B = 0x58f38dedu;
  const uint32_t MIX_L = 0xca01f9ddu, MIX_R = 0x4973f715u;
  uint32_t hc = 0x43b0d7e5u;
  auto hashmix = [&](uint32_t v) -> uint32_t {
    v ^= hc; hc *= MULT_A; v *= hc; v ^= v >> 16; return v;
  };
  auto mix = [&](uint32_t x, uint32_t y) -> uint32_t {
    uint32_t r = (x * MIX_L) - (y * MIX_R); r ^= r >> 16; return r;
  };
  uint32_t pool[4];
  for (int i = 0; i < 4; ++i) pool[i] = hashmix(i == 0 ? 1234u : 0u);
  for (int s = 0; s < 4; ++s)
    for (int d = 0; d < 4; ++d)
      if (s != d) pool[d] = mix(pool[d], hashmix(pool[s]));
  uint32_t st32[8];
  uint32_t hcb = INIT_B;
  for (int i = 0; i < 8; ++i) {
    uint32_t dv = pool[i & 3];
    dv ^= hcb; hcb *= MULT_B; dv *= hcb; dv ^= dv >> 16;
    st32[i] = dv;
  }
  uint64_t s64[4];
  for (int k = 0; k < 4; ++k) s64[k] = (uint64_t)st32[2 * k] | ((uint64_t)st32[2 * k + 1] << 32);
  const __uint128_t M = ((__uint128_t)0x2360ed051fc65da4ULL << 64) | 0x4385df649fccf645ULL;
  __uint128_t initstate = ((__uint128_t)s64[0] << 64) | s64[1];
  __uint128_t inc = ((((__uint128_t)s64[2] << 64) | s64[3]) << 1) | (__uint128_t)1;
  __uint128_t state = inc;
  state += initstate;
  state = state * M + inc;
  bool has = false; uint32_t hbuf = 0;
  auto next32 = [&]() -> uint32_t {
    if (has) { has = false; return hbuf; }
    state = state * M + inc;
    uint64_t hi = (uint64_t)(state >> 64), lo = (uint64_t)state;
    uint64_t x = hi ^ lo;
    unsigned rot = (unsigned)(state >> 122) & 63u;
    uint64_t o = (x >> rot) | (x << ((64u - rot) & 63u));
    has = true; hbuf = (uint32_t)(o >> 32);
    return (uint32_t)o;
  };
  for (int i = 0; i < 20; ++i) {
    kinds[i] = (int)(((uint64_t)next32() * 4ull) >> 32);
    wires[i] = (int)(((uint64_t)next32() * 4ull) >> 32);
  }
}

// ---------------------------------------------------------------------------
// bf16 hi/lo split helpers.
// ---------------------------------------------------------------------------
static __device__ __forceinline__ unsigned short bf16_rn(float x) {
  uint32_t u = __float_as_uint(x);
  return (unsigned short)((u + 0x7FFFu + ((u >> 16) & 1u)) >> 16);
}
static __device__ __forceinline__ void split2(float x, unsigned short& h, unsigned short& l) {
  h = bf16_rn(x);
  float hf = __uint_as_float(((uint32_t)h) << 16);
  l = bf16_rn(x - hf);
}

// ---------------------------------------------------------------------------
// prep (R11/R12/R14-verified): block 2304 builds the 3^4 tensors T; blocks
// 0..2303 split x/wqkv/wout to bf16 hi/lo.
// ---------------------------------------------------------------------------
__global__ __launch_bounds__(256) void prep(
    const float* __restrict__ rand_angles, const float* __restrict__ rx_theta,
    const float* __restrict__ ry_theta, unsigned long long kinds,
    unsigned long long wires, float* __restrict__ Tg,
    const float* __restrict__ x, unsigned short* __restrict__ xh, unsigned short* __restrict__ xl,
    const float* __restrict__ wq, unsigned short* __restrict__ wh, unsigned short* __restrict__ wl,
    const float* __restrict__ wo, unsigned short* __restrict__ woh, unsigned short* __restrict__ wol)
{
  __shared__ float Ur[16][16], Ui[16][16];
  __shared__ float Msh[4][16][16];
  const int bid = blockIdx.x;
  const int tid = threadIdx.x;
  if (bid < 2304) {
    const float* in; unsigned short *h, *l; int i;
    if (bid < 2048)      { in = x;  h = xh;  l = xl;  i = bid * 256 + tid; }
    else if (bid < 2240) { in = wq; h = wh;  l = wl;  i = (bid - 2048) * 256 + tid; }
    else                 { in = wo; h = woh; l = wol; i = (bid - 2240) * 256 + tid; }
    float4 v = *reinterpret_cast<const float4*>(&in[(size_t)i * 4]);
    ushort4 hh, ll;
    split2(v.x, hh.x, ll.x);
    split2(v.y, hh.y, ll.y);
    split2(v.z, hh.z, ll.z);
    split2(v.w, hh.w, ll.w);
    *reinterpret_cast<ushort4*>(&h[(size_t)i * 4]) = hh;
    *reinterpret_cast<ushort4*>(&l[(size_t)i * 4]) = ll;
    return;
  }
  // ---- build_tables (verified R2-R14) ----
  {
    int i = tid >> 4, j = tid & 15;
    Ur[i][j] = (i == j) ? 1.0f : 0.0f;
    Ui[i][j] = 0.0f;
  }
  __syncthreads();
  for (int g = 0; g < 28; ++g) {
    int kind, w; float th;
    if (g < 20) {
      kind = (int)((kinds >> (2 * g)) & 3ull);
      w = (int)((wires >> (2 * g)) & 3ull);
      th = rand_angles[g];
    } else {
      int e = g - 20;
      w = e >> 1;
      kind = (e & 1) ? 1 : 0;
      th = (e & 1) ? ry_theta[0] : rx_theta[0];
    }
    if (kind == 3) {
      int mc = 8 >> w, mt = 8 >> ((w + 1) & 3);
      if (tid < 64) {
        int pi = tid >> 4, j = tid & 15;
        int i = mc, pbit = 0;
        for (int b = 3; b >= 0; --b) {
          int mask = 1 << b;
          if (mask != mc && mask != mt) { i |= ((pi >> pbit) & 1) << b; pbit++; }
        }
        int i2 = i | mt;
        float tr = Ur[i][j], ti = Ui[i][j];
        Ur[i][j] = Ur[i2][j]; Ui[i][j] = Ui[i2][j];
        Ur[i2][j] = tr; Ui[i2][j] = ti;
      }
    } else {
      float s, c;
      sincosf(th * 0.5f, &s, &c);
      float g00r, g00i, g01r, g01i, g10r, g10i, g11r, g11i;
      if (kind == 0) {
        g00r = c; g00i = 0; g01r = 0; g01i = -s; g10r = 0; g10i = -s; g11r = c; g11i = 0;
      } else if (kind == 1) {
        g00r = c; g00i = 0; g01r = -s; g01i = 0; g10r = s; g10i = 0; g11r = c; g11i = 0;
      } else {
        g00r = c; g00i = -s; g01r = 0; g01i = 0; g10r = 0; g10i = 0; g11r = c; g11i = s;
      }
      if (tid < 128) {
        int p = tid >> 4, j = tid & 15;
        int mb = 3 - w;
        int i0 = ((p >> mb) << (mb + 1)) | (p & ((1 << mb) - 1));
        int i1 = i0 | (1 << mb);
        float ar = Ur[i0][j], ai = Ui[i0][j];
        float br = Ur[i1][j], bi = Ui[i1][j];
        Ur[i0][j] = g00r * ar - g00i * ai + g01r * br - g01i * bi;
        Ui[i0][j] = g00r * ai + g00i * ar + g01r * bi + g01i * br;
        Ur[i1][j] = g10r * ar - g10i * ai + g11r * br - g11i * bi;
        Ui[i1][j] = g10r * ai + g10i * ar + g11r * bi + g11i * br;
      }
    }
    __syncthreads();
  }
  {
    int j = tid >> 4, k = tid & 15;
    float m0 = 0, m1 = 0, m2 = 0, m3 = 0;
#pragma unroll
    for (int l = 0; l < 16; ++l) {
      float p = Ur[l][j] * Ur[l][k] + Ui[l][j] * Ui[l][k];
      m0 += (l & 8) ? -p : p;
      m1 += (l & 4) ? -p : p;
      m2 += (l & 2) ? -p : p;
      m3 += (l & 1) ? -p : p;
    }
    Msh[0][j][k] = m0; Msh[1][j][k] = m1; Msh[2][j][k] = m2; Msh[3][j][k] = m3;
  }
  __syncthreads();
  if (tid < 81) {
    int e4 = tid % 3, r = tid / 3;
    int ee0 = r / 9, ee1 = (r / 3) % 3, ee2 = r % 3;
    int ee[4] = { ee0, ee1, ee2, e4 };
    float s0 = 0, s1 = 0, s2 = 0, s3 = 0;
    for (int m = 0; m < 16; ++m) {
      int j = 0, k = 0; float coef = 1.0f;
      for (int i = 0; i < 4; ++i) {
        int o = (m >> i) & 1;
        int e = ee[i];
        int bj, bk; float c;
        if (e == 2)      { bj = o; bk = 1 - o; c = 0.5f; }
        else if (e == 1) { bj = o; bk = o;     c = o ? -0.5f : 0.5f; }
        else             { bj = o; bk = o;     c = 0.5f; }
        j |= bj << (3 - i); k |= bk << (3 - i);
        coef *= c;
      }
      s0 += coef * Msh[0][j][k]; s1 += coef * Msh[1][j][k];
      s2 += coef * Msh[2][j][k]; s3 += coef * Msh[3][j][k];
    }
    Tg[(0 * 27 + r) * 4 + e4] = s0;
    Tg[(1 * 27 + r) * 4 + e4] = s1;
    Tg[(2 * 27 + r) * 4 + e4] = s2;
    Tg[(3 * 27 + r) * 4 + e4] = s3;
  }
  if (tid >= 81 && tid < 108) {
    int r = tid - 81;
    for (int w = 0; w < 4; ++w) Tg[(w * 27 + r) * 4 + 3] = 0.0f;
  }
}

// ---------------------------------------------------------------------------
// MFMA split-bf16 GEMM (R9/R10/R12/R14-verified): BM=128 BN=64 BK=64,
// XOR-swizzled LDS, XCD-swizzled 1D grid. C = A@B^T (+bias).
// ---------------------------------------------------------------------------
__global__ __launch_bounds__(256) void gemm_bf16s(
    const unsigned short* __restrict__ Ah, const unsigned short* __restrict__ Al,
    const unsigned short* __restrict__ Bh, const unsigned short* __restrict__ Bl,
    const float* __restrict__ bias, float* __restrict__ C,
    int M, int N, int K, int nbx)
{
  __shared__ __align__(16) unsigned short sAh[128 * 64];
  __shared__ __align__(16) unsigned short sAl[128 * 64];
  __shared__ __align__(16) unsigned short sBh[64 * 64];
  __shared__ __align__(16) unsigned short sBl[64 * 64];
  int cpx = gridDim.x >> 3;
  int wg = (blockIdx.x & 7) * cpx + (blockIdx.x >> 3);
  const int bx = wg % nbx, by = wg / nbx;
  const int bm = by * 128, bn = bx * 64;
  const int tid = threadIdx.x;
  const int wave = tid >> 6, lane = tid & 63;
  const int wm = wave >> 1, wn = wave & 1;
  const int fr = lane & 15, fg = lane >> 4;
  floatx4 acc[4][2] = {};
  for (int k0 = 0; k0 < K; k0 += 64) {
    __syncthreads();
#pragma unroll
    for (int rd = 0; rd < 4; ++rd) {
      int idx = tid + rd * 256;
      int row = idx >> 3, s = idx & 7;
      int ss = s ^ (row & 7);
      size_t go = (size_t)(bm + row) * K + k0 + s * 8;
      *reinterpret_cast<uint4*>(&sAh[(row * 8 + ss) * 8]) =
          *reinterpret_cast<const uint4*>(&Ah[go]);
      *reinterpret_cast<uint4*>(&sAl[(row * 8 + ss) * 8]) =
          *reinterpret_cast<const uint4*>(&Al[go]);
    }
#pragma unroll
    for (int rd = 0; rd < 2; ++rd) {
      int idx = tid + rd * 256;
      int row = idx >> 3, s = idx & 7;
      int ss = s ^ (row & 7);
      size_t go = (size_t)(bn + row) * K + k0 + s * 8;
      *reinterpret_cast<uint4*>(&sBh[(row * 8 + ss) * 8]) =
          *reinterpret_cast<const uint4*>(&Bh[go]);
      *reinterpret_cast<uint4*>(&sBl[(row * 8 + ss) * 8]) =
          *reinterpret_cast<const uint4*>(&Bl[go]);
    }
    __syncthreads();
#pragma unroll
    for (int kk = 0; kk < 2; ++kk) {
      short8 a_h[4], a_l[4], b_h[2], b_l[2];
#pragma unroll
      for (int fm = 0; fm < 4; ++fm) {
        int row = wm * 64 + fm * 16 + fr;
        int ss = (kk * 4 + fg) ^ (row & 7);
        a_h[fm] = *reinterpret_cast<const short8*>(&sAh[(row * 8 + ss) * 8]);
        a_l[fm] = *reinterpret_cast<const short8*>(&sAl[(row * 8 + ss) * 8]);
      }
#pragma unroll
      for (int fn = 0; fn < 2; ++fn) {
        int row = wn * 32 + fn * 16 + fr;
        int ss = (kk * 4 + fg) ^ (row & 7);
        b_h[fn] = *reinterpret_cast<const short8*>(&sBh[(row * 8 + ss) * 8]);
        b_l[fn] = *reinterpret_cast<const short8*>(&sBl[(row * 8 + ss) * 8]);
      }
#pragma unroll
      for (int fm = 0; fm < 4; ++fm)
#pragma unroll
        for (int fn = 0; fn < 2; ++fn) {
          acc[fm][fn] = __builtin_amdgcn_mfma_f32_16x16x32_bf16(a_h[fm], b_h[fn], acc[fm][fn], 0, 0, 0);
          acc[fm][fn] = __builtin_amdgcn_mfma_f32_16x16x32_bf16(a_h[fm], b_l[fn], acc[fm][fn], 0, 0, 0);
          acc[fm][fn] = __builtin_amdgcn_mfma_f32_16x16x32_bf16(a_l[fm], b_h[fn], acc[fm][fn], 0, 0, 0);
        }
    }
  }
#pragma unroll
  for (int fm = 0; fm < 4; ++fm) {
    int rowb = bm + wm * 64 + fm * 16 + fg * 4;
#pragma unroll
    for (int fn = 0; fn < 2; ++fn) {
      int col = bn + wn * 32 + fn * 16 + fr;
      float bv = (bias != nullptr) ? bias[col] : 0.0f;
#pragma unroll
      for (int r = 0; r < 4; ++r)
        C[(size_t)(rowb + r) * N + col] = acc[fm][fn][r] + bv;
    }
  }
}

// ---------------------------------------------------------------------------
// BM=64 GEMM variant (R11/R12/R14-verified) for the small final projection.
// ---------------------------------------------------------------------------
__global__ __launch_bounds__(256) void gemm_bf16s64(
    const unsigned short* __restrict__ Ah, const unsigned short* __restrict__ Al,
    const unsigned short* __restrict__ Bh, const unsigned short* __restrict__ Bl,
    const float* __restrict__ bias, float* __restrict__ C,
    int M, int N, int K, int nbx)
{
  __shared__ __align__(16) unsigned short sAh[64 * 64];
  __shared__ __align__(16) unsigned short sAl[64 * 64];
  __shared__ __align__(16) unsigned short sBh[64 * 64];
  __shared__ __align__(16) unsigned short sBl[64 * 64];
  int cpx = gridDim.x >> 3;
  int wg = (blockIdx.x & 7) * cpx + (blockIdx.x >> 3);
  const int bx = wg % nbx, by = wg / nbx;
  const int bm = by * 64, bn = bx * 64;
  const int tid = threadIdx.x;
  const int wave = tid >> 6, lane = tid & 63;
  const int wm = wave >> 1, wn = wave & 1;
  const int fr = lane & 15, fg = lane >> 4;
  floatx4 acc[2][2] = {};
  for (int k0 = 0; k0 < K; k0 += 64) {
    __syncthreads();
#pragma unroll
    for (int rd = 0; rd < 2; ++rd) {
      int idx = tid + rd * 256;
      int row = idx >> 3, s = idx & 7;
      int ss = s ^ (row & 7);
      size_t goA = (size_t)(bm + row) * K + k0 + s * 8;
      *reinterpret_cast<uint4*>(&sAh[(row * 8 + ss) * 8]) =
          *reinterpret_cast<const uint4*>(&Ah[goA]);
      *reinterpret_cast<uint4*>(&sAl[(row * 8 + ss) * 8]) =
          *reinterpret_cast<const uint4*>(&Al[goA]);
      size_t goB = (size_t)(bn + row) * K + k0 + s * 8;
      *reinterpret_cast<uint4*>(&sBh[(row * 8 + ss) * 8]) =
          *reinterpret_cast<const uint4*>(&Bh[goB]);
      *reinterpret_cast<uint4*>(&sBl[(row * 8 + ss) * 8]) =
          *reinterpret_cast<const uint4*>(&Bl[goB]);
    }
    __syncthreads();
#pragma unroll
    for (int kk = 0; kk < 2; ++kk) {
      short8 a_h[2], a_l[2], b_h[2], b_l[2];
#pragma unroll
      for (int fm = 0; fm < 2; ++fm) {
        int row = wm * 32 + fm * 16 + fr;
        int ss = (kk * 4 + fg) ^ (row & 7);
        a_h[fm] = *reinterpret_cast<const short8*>(&sAh[(row * 8 + ss) * 8]);
        a_l[fm] = *reinterpret_cast<const short8*>(&sAl[(row * 8 + ss) * 8]);
      }
#pragma unroll
      for (int fn = 0; fn < 2; ++fn) {
        int row = wn * 32 + fn * 16 + fr;
        int ss = (kk * 4 + fg) ^ (row & 7);
        b_h[fn] = *reinterpret_cast<const short8*>(&sBh[(row * 8 + ss) * 8]);
        b_l[fn] = *reinterpret_cast<const short8*>(&sBl[(row * 8 + ss) * 8]);
      }
#pragma unroll
      for (int fm = 0; fm < 2; ++fm)
#pragma unroll
        for (int fn = 0; fn < 2; ++fn) {
          acc[fm][fn] = __builtin_amdgcn_mfma_f32_16x16x32_bf16(a_h[fm], b_h[fn], acc[fm][fn], 0, 0, 0);
          acc[fm][fn] = __builtin_amdgcn_mfma_f32_16x16x32_bf16(a_h[fm], b_l[fn], acc[fm][fn], 0, 0, 0);
          acc[fm][fn] = __builtin_amdgcn_mfma_f32_16x16x32_bf16(a_l[fm], b_h[fn], acc[fm][fn], 0, 0, 0);
        }
    }
  }
#pragma unroll
  for (int fm = 0; fm < 2; ++fm) {
    int rowb = bm + wm * 32 + fm * 16 + fg * 4;
#pragma unroll
    for (int fn = 0; fn < 2; ++fn) {
      int col = bn + wn * 32 + fn * 16 + fr;
      float bv = (bias != nullptr) ? bias[col] : 0.0f;
#pragma unroll
      for (int r = 0; r < 4; ++r)
        C[(size_t)(rowb + r) * N + col] = acc[fm][fn][r] + bv;
    }
  }
}

// ---------------------------------------------------------------------------
// Quantum transform, 1 vector/thread (triple-proven apply1 body), with
// __launch_bounds__(256, 8): force <=64 VGPR so 8 waves/SIMD hide the
// sincos + T-load latency chains (G1/G6). Live state is small (cv/sv 8 +
// acc tier 3 + z 4); the bound throttles the compiler's load batching.
// ---------------------------------------------------------------------------
__global__ __launch_bounds__(256, 8) void quantum_apply1_hb(
    float* __restrict__ p0, const float* __restrict__ Tg)
{
  size_t base = ((size_t)blockIdx.x * 256 + threadIdx.x) * 4;
  float4 A = *reinterpret_cast<const float4*>(&p0[base]);
  float cv[4], sv[4];
  __sincosf(A.x, &sv[0], &cv[0]);
  __sincosf(A.y, &sv[1], &cv[1]);
  __sincosf(A.z, &sv[2], &cv[2]);
  __sincosf(A.w, &sv[3], &cv[3]);
  float z[4];
#pragma unroll
  for (int w = 0; w < 4; ++w) {
    float a1_ = 0.f;
#pragma unroll
    for (int e1 = 0; e1 < 3; ++e1) {
      float a2_ = 0.f;
#pragma unroll
      for (int e2 = 0; e2 < 3; ++e2) {
        float a3_ = 0.f;
#pragma unroll
        for (int e3 = 0; e3 < 3; ++e3) {
          const float4 t4 = *reinterpret_cast<const float4*>(
              &Tg[(w * 27 + e1 * 9 + e2 * 3 + e3) * 4]);
          float inner = fmaf(sv[3], t4.z, fmaf(cv[3], t4.y, t4.x));
          if (e3 == 0)      a3_ += inner;
          else if (e3 == 1) a3_ = fmaf(inner, cv[2], a3_);
          else              a3_ = fmaf(inner, sv[2], a3_);
        }
        if (e2 == 0)      a2_ += a3_;
        else if (e2 == 1) a2_ = fmaf(a3_, cv[1], a2_);
        else              a2_ = fmaf(a3_, sv[1], a2_);
      }
      if (e1 == 0)      a1_ += a2_;
      else if (e1 == 1) a1_ = fmaf(a2_, cv[0], a1_);
      else              a1_ = fmaf(a2_, sv[0], a1_);
    }
    z[w] = a1_;
  }
  *reinterpret_cast<float4*>(&p0[base]) = make_float4(z[0], z[1], z[2], z[3]);
}

// ---------------------------------------------------------------------------
// Attention across heads, zero-LDS readlane broadcast (R10/R12/R14-verified).
// Outputs bf16 hi/lo in (B,H,T,D)-flat layout for gemm2.
// ---------------------------------------------------------------------------
static __device__ __forceinline__ float rl(float x, int l) {
  return __int_as_float(__builtin_amdgcn_readlane(__float_as_int(x), l));
}

__global__ __launch_bounds__(256) void attn_rl_b(
    const float* __restrict__ qkv, unsigned short* __restrict__ yh,
    unsigned short* __restrict__ yl)
{
  const int wave = threadIdx.x >> 6, lane = threadIdx.x & 63;
  const int posIdx = blockIdx.x * 4 + wave;   // b*2048 + pos
  const float* row = qkv + (size_t)posIdx * 768;
  float4 q = *reinterpret_cast<const float4*>(&row[lane * 4]);
  float4 k = *reinterpret_cast<const float4*>(&row[256 + lane * 4]);
  float4 v = *reinterpret_cast<const float4*>(&row[512 + lane * 4]);
  float nx = 0, ny = 0, nz = 0, nw = 0, den = 0;
#pragma unroll
  for (int ss = 0; ss < 64; ++ss) {
    float kx = rl(k.x, ss), ky = rl(k.y, ss), kz = rl(k.z, ss), kw = rl(k.w, ss);
    float d = fmaf(q.x, kx, fmaf(q.y, ky, fmaf(q.z, kz, q.w * kw)));
    float e = __expf(d * 0.5f);
    den += e;
    nx = fmaf(e, rl(v.x, ss), nx);
    ny = fmaf(e, rl(v.y, ss), ny);
    nz = fmaf(e, rl(v.z, ss), nz);
    nw = fmaf(e, rl(v.w, ss), nw);
  }
  float inv = 1.0f / den;
  const int b = posIdx >> 11, pos = posIdx & 2047;
  size_t off = (((size_t)(b * 64 + lane)) * 2048 + pos) * 4;
  ushort4 hh, ll;
  split2(nx * inv, hh.x, ll.x);
  split2(ny * inv, hh.y, ll.y);
  split2(nz * inv, hh.z, ll.z);
  split2(nw * inv, hh.w, ll.w);
  *reinterpret_cast<ushort4*>(&yh[off]) = hh;
  *reinterpret_cast<ushort4*>(&yl[off]) = ll;
}

// ---------------------------------------------------------------------------
extern "C" void kernel_launch(void* const* d_in, const int* in_sizes, int n_in,
                              void* d_out, int out_size, void* d_ws, size_t ws_size,
                              hipStream_t stream)
{
  const float* x    = (const float*)d_in[0];
  const float* wqkv = (const float*)d_in[1];
  const float* wout = (const float*)d_in[2];
  const float* bout = (const float*)d_in[3];
  const float* rxth = (const float*)d_in[4];
  const float* ryth = (const float*)d_in[5];
  const float* rang = (const float*)d_in[6];
  float* out = (float*)d_out;

  uint8_t* w8 = (uint8_t*)d_ws;
  float* Tg = (float*)w8;                                  //   4 KB
  float* p0 = (float*)(w8 + 4096);                         //  24 MB (8192x768 f32)
  uint8_t* bb = w8 + 4096 + (size_t)8192 * 768 * 4;
  unsigned short* xh  = (unsigned short*)bb;               // 4 MB
  unsigned short* xl  = xh + (size_t)8192 * 256;           // 4 MB
  unsigned short* wh  = xl + (size_t)8192 * 256;           // 384 KB
  unsigned short* wl  = wh + (size_t)768 * 256;            // 384 KB
  unsigned short* woh = wl + (size_t)768 * 256;            // 128 KB
  unsigned short* wol = woh + (size_t)256 * 256;           // 128 KB
  unsigned short* yh  = wol + (size_t)256 * 256;           // 4 MB
  unsigned short* yl  = yh + (size_t)8192 * 256;           // 4 MB

  int kinds[20], wires[20];
  compute_ops_host(kinds, wires);
  unsigned long long pk = 0, pw = 0;
  for (int i = 0; i < 20; ++i) {
    pk |= (unsigned long long)(kinds[i] & 3) << (2 * i);
    pw |= (unsigned long long)(wires[i] & 3) << (2 * i);
  }

  // 1) build tables + bf16 splits (merged, independent work)
  hipLaunchKernelGGL(prep, dim3(2305), dim3(256), 0, stream,
                     rang, rxth, ryth, pk, pw, Tg,
                     x, xh, xl, wqkv, wh, wl, wout, woh, wol);
  // 2) gemm1: p0 = x @ wqkv^T  (8192x768, K=256); grid 768 (%8==0)
  hipLaunchKernelGGL(gemm_bf16s, dim3(768), dim3(256), 0, stream,
                     xh, xl, wh, wl, (const float*)nullptr, p0, 8192, 768, 256, 12);
  // 3) quantum transform in-place (1 vec/thread, occupancy-bounded)
  hipLaunchKernelGGL(quantum_apply1_hb, dim3(6144), dim3(256), 0, stream, p0, Tg);
  // 4) attention across heads -> bf16 hi/lo y (zero-LDS readlane)
  hipLaunchKernelGGL(attn_rl_b, dim3(2048), dim3(256), 0, stream, p0, yh, yl);
  // 5) gemm2: out = y @ wout^T + bias  (8192x256, K=256); grid 512 (%8==0)
  hipLaunchKernelGGL(gemm_bf16s64, dim3(512), dim3(256), 0, stream,
                     yh, yl, woh, wol, bout, out, 8192, 256, 256, 4);
}

// Round 16
// 87.707 us; speedup vs baseline: 1.0363x; 1.0363x over previous
//
#include <hip/hip_runtime.h>
#include <stdint.h>
#include <stddef.h>

// B=4, T=2048, C=256, H=64, D=4 ; rows = 8192 ; qkv row = [q|k|v] 768 f
typedef __attribute__((ext_vector_type(8))) short short8;
typedef __attribute__((ext_vector_type(4))) float floatx4;
typedef __attribute__((ext_vector_type(2))) float float2v;

// ---------------------------------------------------------------------------
// Host-side np.random.default_rng(1234) op list (verified R2).
// ---------------------------------------------------------------------------
static void compute_ops_host(int* kinds, int* wires) {
  const uint32_t MULT_A = 0x931e8875u;
  const uint32_t INIT_B = 0x8b51f9ddu, MULT_B = 0x58f38dedu;
  const uint32_t MIX_L = 0xca01f9ddu, MIX_R = 0x4973f715u;
  uint32_t hc = 0x43b0d7e5u;
  auto hashmix = [&](uint32_t v) -> uint32_t {
    v ^= hc; hc *= MULT_A; v *= hc; v ^= v >> 16; return v;
  };
  auto mix = [&](uint32_t x, uint32_t y) -> uint32_t {
    uint32_t r = (x * MIX_L) - (y * MIX_R); r ^= r >> 16; return r;
  };
  uint32_t pool[4];
  for (int i = 0; i < 4; ++i) pool[i] = hashmix(i == 0 ? 1234u : 0u);
  for (int s = 0; s < 4; ++s)
    for (int d = 0; d < 4; ++d)
      if (s != d) pool[d] = mix(pool[d], hashmix(pool[s]));
  uint32_t st32[8];
  uint32_t hcb = INIT_B;
  for (int i = 0; i < 8; ++i) {
    uint32_t dv = pool[i & 3];
    dv ^= hcb; hcb *= MULT_B; dv *= hcb; dv ^= dv >> 16;
    st32[i] = dv;
  }
  uint64_t s64[4];
  for (int k = 0; k < 4; ++k) s64[k] = (uint64_t)st32[2 * k] | ((uint64_t)st32[2 * k + 1] << 32);
  const __uint128_t M = ((__uint128_t)0x2360ed051fc65da4ULL << 64) | 0x4385df649fccf645ULL;
  __uint128_t initstate = ((__uint128_t)s64[0] << 64) | s64[1];
  __uint128_t inc = ((((__uint128_t)s64[2] << 64) | s64[3]) << 1) | (__uint128_t)1;
  __uint128_t state = inc;
  state += initstate;
  state = state * M + inc;
  bool has = false; uint32_t hbuf = 0;
  auto next32 = [&]() -> uint32_t {
    if (has) { has = false; return hbuf; }
    state = state * M + inc;
    uint64_t hi = (uint64_t)(state >> 64), lo = (uint64_t)state;
    uint64_t x = hi ^ lo;
    unsigned rot = (unsigned)(state >> 122) & 63u;
    uint64_t o = (x >> rot) | (x << ((64u - rot) & 63u));
    has = true; hbuf = (uint32_t)(o >> 32);
    return (uint32_t)o;
  };
  for (int i = 0; i < 20; ++i) {
    kinds[i] = (int)(((uint64_t)next32() * 4ull) >> 32);
    wires[i] = (int)(((uint64_t)next32() * 4ull) >> 32);
  }
}

// ---------------------------------------------------------------------------
// bf16 hi/lo split helpers.
// ---------------------------------------------------------------------------
static __device__ __forceinline__ unsigned short bf16_rn(float x) {
  uint32_t u = __float_as_uint(x);
  return (unsigned short)((u + 0x7FFFu + ((u >> 16) & 1u)) >> 16);
}
static __device__ __forceinline__ void split2(float x, unsigned short& h, unsigned short& l) {
  h = bf16_rn(x);
  float hf = __uint_as_float(((uint32_t)h) << 16);
  l = bf16_rn(x - hf);
}

// ---------------------------------------------------------------------------
// prep (R11/R12/R14-verified): block 2304 builds the 3^4 tensors T; blocks
// 0..2303 split x/wqkv/wout to bf16 hi/lo.
// ---------------------------------------------------------------------------
__global__ __launch_bounds__(256) void prep(
    const float* __restrict__ rand_angles, const float* __restrict__ rx_theta,
    const float* __restrict__ ry_theta, unsigned long long kinds,
    unsigned long long wires, float* __restrict__ Tg,
    const float* __restrict__ x, unsigned short* __restrict__ xh, unsigned short* __restrict__ xl,
    const float* __restrict__ wq, unsigned short* __restrict__ wh, unsigned short* __restrict__ wl,
    const float* __restrict__ wo, unsigned short* __restrict__ woh, unsigned short* __restrict__ wol)
{
  __shared__ float Ur[16][16], Ui[16][16];
  __shared__ float Msh[4][16][16];
  const int bid = blockIdx.x;
  const int tid = threadIdx.x;
  if (bid < 2304) {
    const float* in; unsigned short *h, *l; int i;
    if (bid < 2048)      { in = x;  h = xh;  l = xl;  i = bid * 256 + tid; }
    else if (bid < 2240) { in = wq; h = wh;  l = wl;  i = (bid - 2048) * 256 + tid; }
    else                 { in = wo; h = woh; l = wol; i = (bid - 2240) * 256 + tid; }
    float4 v = *reinterpret_cast<const float4*>(&in[(size_t)i * 4]);
    ushort4 hh, ll;
    split2(v.x, hh.x, ll.x);
    split2(v.y, hh.y, ll.y);
    split2(v.z, hh.z, ll.z);
    split2(v.w, hh.w, ll.w);
    *reinterpret_cast<ushort4*>(&h[(size_t)i * 4]) = hh;
    *reinterpret_cast<ushort4*>(&l[(size_t)i * 4]) = ll;
    return;
  }
  // ---- build_tables (verified R2-R14) ----
  {
    int i = tid >> 4, j = tid & 15;
    Ur[i][j] = (i == j) ? 1.0f : 0.0f;
    Ui[i][j] = 0.0f;
  }
  __syncthreads();
  for (int g = 0; g < 28; ++g) {
    int kind, w; float th;
    if (g < 20) {
      kind = (int)((kinds >> (2 * g)) & 3ull);
      w = (int)((wires >> (2 * g)) & 3ull);
      th = rand_angles[g];
    } else {
      int e = g - 20;
      w = e >> 1;
      kind = (e & 1) ? 1 : 0;
      th = (e & 1) ? ry_theta[0] : rx_theta[0];
    }
    if (kind == 3) {
      int mc = 8 >> w, mt = 8 >> ((w + 1) & 3);
      if (tid < 64) {
        int pi = tid >> 4, j = tid & 15;
        int i = mc, pbit = 0;
        for (int b = 3; b >= 0; --b) {
          int mask = 1 << b;
          if (mask != mc && mask != mt) { i |= ((pi >> pbit) & 1) << b; pbit++; }
        }
        int i2 = i | mt;
        float tr = Ur[i][j], ti = Ui[i][j];
        Ur[i][j] = Ur[i2][j]; Ui[i][j] = Ui[i2][j];
        Ur[i2][j] = tr; Ui[i2][j] = ti;
      }
    } else {
      float s, c;
      sincosf(th * 0.5f, &s, &c);
      float g00r, g00i, g01r, g01i, g10r, g10i, g11r, g11i;
      if (kind == 0) {
        g00r = c; g00i = 0; g01r = 0; g01i = -s; g10r = 0; g10i = -s; g11r = c; g11i = 0;
      } else if (kind == 1) {
        g00r = c; g00i = 0; g01r = -s; g01i = 0; g10r = s; g10i = 0; g11r = c; g11i = 0;
      } else {
        g00r = c; g00i = -s; g01r = 0; g01i = 0; g10r = 0; g10i = 0; g11r = c; g11i = s;
      }
      if (tid < 128) {
        int p = tid >> 4, j = tid & 15;
        int mb = 3 - w;
        int i0 = ((p >> mb) << (mb + 1)) | (p & ((1 << mb) - 1));
        int i1 = i0 | (1 << mb);
        float ar = Ur[i0][j], ai = Ui[i0][j];
        float br = Ur[i1][j], bi = Ui[i1][j];
        Ur[i0][j] = g00r * ar - g00i * ai + g01r * br - g01i * bi;
        Ui[i0][j] = g00r * ai + g00i * ar + g01r * bi + g01i * br;
        Ur[i1][j] = g10r * ar - g10i * ai + g11r * br - g11i * bi;
        Ui[i1][j] = g10r * ai + g10i * ar + g11r * bi + g11i * br;
      }
    }
    __syncthreads();
  }
  {
    int j = tid >> 4, k = tid & 15;
    float m0 = 0, m1 = 0, m2 = 0, m3 = 0;
#pragma unroll
    for (int l = 0; l < 16; ++l) {
      float p = Ur[l][j] * Ur[l][k] + Ui[l][j] * Ui[l][k];
      m0 += (l & 8) ? -p : p;
      m1 += (l & 4) ? -p : p;
      m2 += (l & 2) ? -p : p;
      m3 += (l & 1) ? -p : p;
    }
    Msh[0][j][k] = m0; Msh[1][j][k] = m1; Msh[2][j][k] = m2; Msh[3][j][k] = m3;
  }
  __syncthreads();
  if (tid < 81) {
    int e4 = tid % 3, r = tid / 3;
    int ee0 = r / 9, ee1 = (r / 3) % 3, ee2 = r % 3;
    int ee[4] = { ee0, ee1, ee2, e4 };
    float s0 = 0, s1 = 0, s2 = 0, s3 = 0;
    for (int m = 0; m < 16; ++m) {
      int j = 0, k = 0; float coef = 1.0f;
      for (int i = 0; i < 4; ++i) {
        int o = (m >> i) & 1;
        int e = ee[i];
        int bj, bk; float c;
        if (e == 2)      { bj = o; bk = 1 - o; c = 0.5f; }
        else if (e == 1) { bj = o; bk = o;     c = o ? -0.5f : 0.5f; }
        else             { bj = o; bk = o;     c = 0.5f; }
        j |= bj << (3 - i); k |= bk << (3 - i);
        coef *= c;
      }
      s0 += coef * Msh[0][j][k]; s1 += coef * Msh[1][j][k];
      s2 += coef * Msh[2][j][k]; s3 += coef * Msh[3][j][k];
    }
    Tg[(0 * 27 + r) * 4 + e4] = s0;
    Tg[(1 * 27 + r) * 4 + e4] = s1;
    Tg[(2 * 27 + r) * 4 + e4] = s2;
    Tg[(3 * 27 + r) * 4 + e4] = s3;
  }
  if (tid >= 81 && tid < 108) {
    int r = tid - 81;
    for (int w = 0; w < 4; ++w) Tg[(w * 27 + r) * 4 + 3] = 0.0f;
  }
}

// ---------------------------------------------------------------------------
// MFMA split-bf16 GEMM (R9/R10/R12/R14-verified): BM=128 BN=64 BK=64,
// XOR-swizzled LDS, XCD-swizzled 1D grid. C = A@B^T (+bias).
// ---------------------------------------------------------------------------
__global__ __launch_bounds__(256) void gemm_bf16s(
    const unsigned short* __restrict__ Ah, const unsigned short* __restrict__ Al,
    const unsigned short* __restrict__ Bh, const unsigned short* __restrict__ Bl,
    const float* __restrict__ bias, float* __restrict__ C,
    int M, int N, int K, int nbx)
{
  __shared__ __align__(16) unsigned short sAh[128 * 64];
  __shared__ __align__(16) unsigned short sAl[128 * 64];
  __shared__ __align__(16) unsigned short sBh[64 * 64];
  __shared__ __align__(16) unsigned short sBl[64 * 64];
  int cpx = gridDim.x >> 3;
  int wg = (blockIdx.x & 7) * cpx + (blockIdx.x >> 3);
  const int bx = wg % nbx, by = wg / nbx;
  const int bm = by * 128, bn = bx * 64;
  const int tid = threadIdx.x;
  const int wave = tid >> 6, lane = tid & 63;
  const int wm = wave >> 1, wn = wave & 1;
  const int fr = lane & 15, fg = lane >> 4;
  floatx4 acc[4][2] = {};
  for (int k0 = 0; k0 < K; k0 += 64) {
    __syncthreads();
#pragma unroll
    for (int rd = 0; rd < 4; ++rd) {
      int idx = tid + rd * 256;
      int row = idx >> 3, s = idx & 7;
      int ss = s ^ (row & 7);
      size_t go = (size_t)(bm + row) * K + k0 + s * 8;
      *reinterpret_cast<uint4*>(&sAh[(row * 8 + ss) * 8]) =
          *reinterpret_cast<const uint4*>(&Ah[go]);
      *reinterpret_cast<uint4*>(&sAl[(row * 8 + ss) * 8]) =
          *reinterpret_cast<const uint4*>(&Al[go]);
    }
#pragma unroll
    for (int rd = 0; rd < 2; ++rd) {
      int idx = tid + rd * 256;
      int row = idx >> 3, s = idx & 7;
      int ss = s ^ (row & 7);
      size_t go = (size_t)(bn + row) * K + k0 + s * 8;
      *reinterpret_cast<uint4*>(&sBh[(row * 8 + ss) * 8]) =
          *reinterpret_cast<const uint4*>(&Bh[go]);
      *reinterpret_cast<uint4*>(&sBl[(row * 8 + ss) * 8]) =
          *reinterpret_cast<const uint4*>(&Bl[go]);
    }
    __syncthreads();
#pragma unroll
    for (int kk = 0; kk < 2; ++kk) {
      short8 a_h[4], a_l[4], b_h[2], b_l[2];
#pragma unroll
      for (int fm = 0; fm < 4; ++fm) {
        int row = wm * 64 + fm * 16 + fr;
        int ss = (kk * 4 + fg) ^ (row & 7);
        a_h[fm] = *reinterpret_cast<const short8*>(&sAh[(row * 8 + ss) * 8]);
        a_l[fm] = *reinterpret_cast<const short8*>(&sAl[(row * 8 + ss) * 8]);
      }
#pragma unroll
      for (int fn = 0; fn < 2; ++fn) {
        int row = wn * 32 + fn * 16 + fr;
        int ss = (kk * 4 + fg) ^ (row & 7);
        b_h[fn] = *reinterpret_cast<const short8*>(&sBh[(row * 8 + ss) * 8]);
        b_l[fn] = *reinterpret_cast<const short8*>(&sBl[(row * 8 + ss) * 8]);
      }
#pragma unroll
      for (int fm = 0; fm < 4; ++fm)
#pragma unroll
        for (int fn = 0; fn < 2; ++fn) {
          acc[fm][fn] = __builtin_amdgcn_mfma_f32_16x16x32_bf16(a_h[fm], b_h[fn], acc[fm][fn], 0, 0, 0);
          acc[fm][fn] = __builtin_amdgcn_mfma_f32_16x16x32_bf16(a_h[fm], b_l[fn], acc[fm][fn], 0, 0, 0);
          acc[fm][fn] = __builtin_amdgcn_mfma_f32_16x16x32_bf16(a_l[fm], b_h[fn], acc[fm][fn], 0, 0, 0);
        }
    }
  }
#pragma unroll
  for (int fm = 0; fm < 4; ++fm) {
    int rowb = bm + wm * 64 + fm * 16 + fg * 4;
#pragma unroll
    for (int fn = 0; fn < 2; ++fn) {
      int col = bn + wn * 32 + fn * 16 + fr;
      float bv = (bias != nullptr) ? bias[col] : 0.0f;
#pragma unroll
      for (int r = 0; r < 4; ++r)
        C[(size_t)(rowb + r) * N + col] = acc[fm][fn][r] + bv;
    }
  }
}

// ---------------------------------------------------------------------------
// BM=64 GEMM variant (R11/R12/R14-verified) for the small final projection.
// ---------------------------------------------------------------------------
__global__ __launch_bounds__(256) void gemm_bf16s64(
    const unsigned short* __restrict__ Ah, const unsigned short* __restrict__ Al,
    const unsigned short* __restrict__ Bh, const unsigned short* __restrict__ Bl,
    const float* __restrict__ bias, float* __restrict__ C,
    int M, int N, int K, int nbx)
{
  __shared__ __align__(16) unsigned short sAh[64 * 64];
  __shared__ __align__(16) unsigned short sAl[64 * 64];
  __shared__ __align__(16) unsigned short sBh[64 * 64];
  __shared__ __align__(16) unsigned short sBl[64 * 64];
  int cpx = gridDim.x >> 3;
  int wg = (blockIdx.x & 7) * cpx + (blockIdx.x >> 3);
  const int bx = wg % nbx, by = wg / nbx;
  const int bm = by * 64, bn = bx * 64;
  const int tid = threadIdx.x;
  const int wave = tid >> 6, lane = tid & 63;
  const int wm = wave >> 1, wn = wave & 1;
  const int fr = lane & 15, fg = lane >> 4;
  floatx4 acc[2][2] = {};
  for (int k0 = 0; k0 < K; k0 += 64) {
    __syncthreads();
#pragma unroll
    for (int rd = 0; rd < 2; ++rd) {
      int idx = tid + rd * 256;
      int row = idx >> 3, s = idx & 7;
      int ss = s ^ (row & 7);
      size_t goA = (size_t)(bm + row) * K + k0 + s * 8;
      *reinterpret_cast<uint4*>(&sAh[(row * 8 + ss) * 8]) =
          *reinterpret_cast<const uint4*>(&Ah[goA]);
      *reinterpret_cast<uint4*>(&sAl[(row * 8 + ss) * 8]) =
          *reinterpret_cast<const uint4*>(&Al[goA]);
      size_t goB = (size_t)(bn + row) * K + k0 + s * 8;
      *reinterpret_cast<uint4*>(&sBh[(row * 8 + ss) * 8]) =
          *reinterpret_cast<const uint4*>(&Bh[goB]);
      *reinterpret_cast<uint4*>(&sBl[(row * 8 + ss) * 8]) =
          *reinterpret_cast<const uint4*>(&Bl[goB]);
    }
    __syncthreads();
#pragma unroll
    for (int kk = 0; kk < 2; ++kk) {
      short8 a_h[2], a_l[2], b_h[2], b_l[2];
#pragma unroll
      for (int fm = 0; fm < 2; ++fm) {
        int row = wm * 32 + fm * 16 + fr;
        int ss = (kk * 4 + fg) ^ (row & 7);
        a_h[fm] = *reinterpret_cast<const short8*>(&sAh[(row * 8 + ss) * 8]);
        a_l[fm] = *reinterpret_cast<const short8*>(&sAl[(row * 8 + ss) * 8]);
      }
#pragma unroll
      for (int fn = 0; fn < 2; ++fn) {
        int row = wn * 32 + fn * 16 + fr;
        int ss = (kk * 4 + fg) ^ (row & 7);
        b_h[fn] = *reinterpret_cast<const short8*>(&sBh[(row * 8 + ss) * 8]);
        b_l[fn] = *reinterpret_cast<const short8*>(&sBl[(row * 8 + ss) * 8]);
      }
#pragma unroll
      for (int fm = 0; fm < 2; ++fm)
#pragma unroll
        for (int fn = 0; fn < 2; ++fn) {
          acc[fm][fn] = __builtin_amdgcn_mfma_f32_16x16x32_bf16(a_h[fm], b_h[fn], acc[fm][fn], 0, 0, 0);
          acc[fm][fn] = __builtin_amdgcn_mfma_f32_16x16x32_bf16(a_h[fm], b_l[fn], acc[fm][fn], 0, 0, 0);
          acc[fm][fn] = __builtin_amdgcn_mfma_f32_16x16x32_bf16(a_l[fm], b_h[fn], acc[fm][fn], 0, 0, 0);
        }
    }
  }
#pragma unroll
  for (int fm = 0; fm < 2; ++fm) {
    int rowb = bm + wm * 32 + fm * 16 + fg * 4;
#pragma unroll
    for (int fn = 0; fn < 2; ++fn) {
      int col = bn + wn * 32 + fn * 16 + fr;
      float bv = (bias != nullptr) ? bias[col] : 0.0f;
#pragma unroll
      for (int r = 0; r < 4; ++r)
        C[(size_t)(rowb + r) * N + col] = acc[fm][fn][r] + bv;
    }
  }
}

// ---------------------------------------------------------------------------
// Quantum transform, 2 vectors/thread (R14-verified best, 88.0us total):
// float2 lanes carry {vec0, vec1}; T broadcast as scalars (54 wave-uniform
// load issues per vector, half of apply1's 108).
// ---------------------------------------------------------------------------
static __device__ __forceinline__ float2v splat2(float s) {
  return (float2v){ s, s };
}
static __device__ __forceinline__ float2v fma2(float2v a, float2v b, float2v c) {
  return __builtin_elementwise_fma(a, b, c);
}

__global__ __launch_bounds__(256) void quantum_pk2(
    float* __restrict__ p0, const float* __restrict__ Tg)
{
  size_t base = ((size_t)blockIdx.x * 256 + threadIdx.x) * 8;
  float4 A0 = *reinterpret_cast<const float4*>(&p0[base]);
  float4 A1 = *reinterpret_cast<const float4*>(&p0[base + 4]);
  float2v cv[4], sv[4];
  {
    float s0, c0, s1, c1;
    __sincosf(A0.x, &s0, &c0); __sincosf(A1.x, &s1, &c1);
    sv[0] = (float2v){ s0, s1 }; cv[0] = (float2v){ c0, c1 };
    __sincosf(A0.y, &s0, &c0); __sincosf(A1.y, &s1, &c1);
    sv[1] = (float2v){ s0, s1 }; cv[1] = (float2v){ c0, c1 };
    __sincosf(A0.z, &s0, &c0); __sincosf(A1.z, &s1, &c1);
    sv[2] = (float2v){ s0, s1 }; cv[2] = (float2v){ c0, c1 };
    __sincosf(A0.w, &s0, &c0); __sincosf(A1.w, &s1, &c1);
    sv[3] = (float2v){ s0, s1 }; cv[3] = (float2v){ c0, c1 };
  }
  float2v z[4];
#pragma unroll
  for (int w = 0; w < 4; ++w) {
    float2v a1_ = splat2(0.f);
#pragma unroll
    for (int e1 = 0; e1 < 3; ++e1) {
      float2v a2_ = splat2(0.f);
#pragma unroll
      for (int e2 = 0; e2 < 3; ++e2) {
        float2v a3_ = splat2(0.f);
#pragma unroll
        for (int e3 = 0; e3 < 3; ++e3) {
          const float4 t4 = *reinterpret_cast<const float4*>(
              &Tg[(w * 27 + e1 * 9 + e2 * 3 + e3) * 4]);
          float2v inner = fma2(sv[3], splat2(t4.z),
                               fma2(cv[3], splat2(t4.y), splat2(t4.x)));
          if (e3 == 0)      a3_ = a3_ + inner;
          else if (e3 == 1) a3_ = fma2(inner, cv[2], a3_);
          else              a3_ = fma2(inner, sv[2], a3_);
        }
        if (e2 == 0)      a2_ = a2_ + a3_;
        else if (e2 == 1) a2_ = fma2(a3_, cv[1], a2_);
        else              a2_ = fma2(a3_, sv[1], a2_);
      }
      if (e1 == 0)      a1_ = a1_ + a2_;
      else if (e1 == 1) a1_ = fma2(a2_, cv[0], a1_);
      else              a1_ = fma2(a2_, sv[0], a1_);
    }
    z[w] = a1_;
  }
  *reinterpret_cast<float4*>(&p0[base])     = make_float4(z[0].x, z[1].x, z[2].x, z[3].x);
  *reinterpret_cast<float4*>(&p0[base + 4]) = make_float4(z[0].y, z[1].y, z[2].y, z[3].y);
}

// ---------------------------------------------------------------------------
// Attention across heads, zero-LDS readlane broadcast (R10/R12/R14-verified).
// Outputs bf16 hi/lo in (B,H,T,D)-flat layout for gemm2.
// ---------------------------------------------------------------------------
static __device__ __forceinline__ float rl(float x, int l) {
  return __int_as_float(__builtin_amdgcn_readlane(__float_as_int(x), l));
}

__global__ __launch_bounds__(256) void attn_rl_b(
    const float* __restrict__ qkv, unsigned short* __restrict__ yh,
    unsigned short* __restrict__ yl)
{
  const int wave = threadIdx.x >> 6, lane = threadIdx.x & 63;
  const int posIdx = blockIdx.x * 4 + wave;   // b*2048 + pos
  const float* row = qkv + (size_t)posIdx * 768;
  float4 q = *reinterpret_cast<const float4*>(&row[lane * 4]);
  float4 k = *reinterpret_cast<const float4*>(&row[256 + lane * 4]);
  float4 v = *reinterpret_cast<const float4*>(&row[512 + lane * 4]);
  float nx = 0, ny = 0, nz = 0, nw = 0, den = 0;
#pragma unroll
  for (int ss = 0; ss < 64; ++ss) {
    float kx = rl(k.x, ss), ky = rl(k.y, ss), kz = rl(k.z, ss), kw = rl(k.w, ss);
    float d = fmaf(q.x, kx, fmaf(q.y, ky, fmaf(q.z, kz, q.w * kw)));
    float e = __expf(d * 0.5f);
    den += e;
    nx = fmaf(e, rl(v.x, ss), nx);
    ny = fmaf(e, rl(v.y, ss), ny);
    nz = fmaf(e, rl(v.z, ss), nz);
    nw = fmaf(e, rl(v.w, ss), nw);
  }
  float inv = 1.0f / den;
  const int b = posIdx >> 11, pos = posIdx & 2047;
  size_t off = (((size_t)(b * 64 + lane)) * 2048 + pos) * 4;
  ushort4 hh, ll;
  split2(nx * inv, hh.x, ll.x);
  split2(ny * inv, hh.y, ll.y);
  split2(nz * inv, hh.z, ll.z);
  split2(nw * inv, hh.w, ll.w);
  *reinterpret_cast<ushort4*>(&yh[off]) = hh;
  *reinterpret_cast<ushort4*>(&yl[off]) = ll;
}

// ---------------------------------------------------------------------------
extern "C" void kernel_launch(void* const* d_in, const int* in_sizes, int n_in,
                              void* d_out, int out_size, void* d_ws, size_t ws_size,
                              hipStream_t stream)
{
  const float* x    = (const float*)d_in[0];
  const float* wqkv = (const float*)d_in[1];
  const float* wout = (const float*)d_in[2];
  const float* bout = (const float*)d_in[3];
  const float* rxth = (const float*)d_in[4];
  const float* ryth = (const float*)d_in[5];
  const float* rang = (const float*)d_in[6];
  float* out = (float*)d_out;

  uint8_t* w8 = (uint8_t*)d_ws;
  float* Tg = (float*)w8;                                  //   4 KB
  float* p0 = (float*)(w8 + 4096);                         //  24 MB (8192x768 f32)
  uint8_t* bb = w8 + 4096 + (size_t)8192 * 768 * 4;
  unsigned short* xh  = (unsigned short*)bb;               // 4 MB
  unsigned short* xl  = xh + (size_t)8192 * 256;           // 4 MB
  unsigned short* wh  = xl + (size_t)8192 * 256;           // 384 KB
  unsigned short* wl  = wh + (size_t)768 * 256;            // 384 KB
  unsigned short* woh = wl + (size_t)768 * 256;            // 128 KB
  unsigned short* wol = woh + (size_t)256 * 256;           // 128 KB
  unsigned short* yh  = wol + (size_t)256 * 256;           // 4 MB
  unsigned short* yl  = yh + (size_t)8192 * 256;           // 4 MB

  int kinds[20], wires[20];
  compute_ops_host(kinds, wires);
  unsigned long long pk = 0, pw = 0;
  for (int i = 0; i < 20; ++i) {
    pk |= (unsigned long long)(kinds[i] & 3) << (2 * i);
    pw |= (unsigned long long)(wires[i] & 3) << (2 * i);
  }

  // 1) build tables + bf16 splits (merged, independent work)
  hipLaunchKernelGGL(prep, dim3(2305), dim3(256), 0, stream,
                     rang, rxth, ryth, pk, pw, Tg,
                     x, xh, xl, wqkv, wh, wl, wout, woh, wol);
  // 2) gemm1: p0 = x @ wqkv^T  (8192x768, K=256); grid 768 (%8==0)
  hipLaunchKernelGGL(gemm_bf16s, dim3(768), dim3(256), 0, stream,
                     xh, xl, wh, wl, (const float*)nullptr, p0, 8192, 768, 256, 12);
  // 3) quantum transform in-place (packed fp32, 2 vec/thread)
  hipLaunchKernelGGL(quantum_pk2, dim3(3072), dim3(256), 0, stream, p0, Tg);
  // 4) attention across heads -> bf16 hi/lo y (zero-LDS readlane)
  hipLaunchKernelGGL(attn_rl_b, dim3(2048), dim3(256), 0, stream, p0, yh, yl);
  // 5) gemm2: out = y @ wout^T + bias  (8192x256, K=256); grid 512 (%8==0)
  hipLaunchKernelGGL(gemm_bf16s64, dim3(512), dim3(256), 0, stream,
                     yh, yl, woh, wol, bout, out, 8192, 256, 256, 4);
}